// Round 3
// baseline (2734.105 us; speedup 1.0000x reference)
//
#include <hip/hip_runtime.h>
#include <hip/hip_fp16.h>

#define NB     64        // batch
#define NB2    32        // half2 (or float2) per node row
#define NNODES 200000
#define NSTEPS 6
#define NEDGES 1000000
#define NIN    4096
#define NOUT   1024

// A[n] = state (fp16, gather source)
// B[n] = state + bias (fp32, atomic accumulation target)

// init: A = 0, B = bias, flag = 0  (ws is poisoned 0xAA each call)
__global__ void init_kernel(const float* __restrict__ bias,
                            __half2* __restrict__ A,
                            float2* __restrict__ B,
                            int* __restrict__ flag) {
    int tid = blockIdx.x * blockDim.x + threadIdx.x;
    int n = tid >> 5;
    int sub = tid & 31;
    if (n >= NNODES) return;
    size_t idx = (size_t)n * NB2 + sub;
    A[idx] = __floats2half2_rn(0.f, 0.f);
    float bn = bias[n];
    B[idx] = make_float2(bn, bn);
    if (sub == 0) flag[n] = 0;
}

// input phase: nodes i < NIN get s = tanh(x*w_in + bias); A = s, B = s + bias
__global__ void input_kernel(const float* __restrict__ x,
                             const float* __restrict__ w_in,
                             const float* __restrict__ bias,
                             __half2* __restrict__ A,
                             float2* __restrict__ B) {
    int tid = blockIdx.x * blockDim.x + threadIdx.x;
    int i = tid >> 5;
    int sub = tid & 31;
    if (i >= NIN) return;
    float wi = w_in[i];
    float bi = bias[i];
    int b0 = sub * 2;
    float v0 = tanhf(x[(size_t)b0 * NIN + i] * wi + bi);
    float v1 = tanhf(x[(size_t)(b0 + 1) * NIN + i] * wi + bi);
    size_t idx = (size_t)i * NB2 + sub;
    A[idx] = __floats2half2_rn(v0, v1);
    B[idx] = make_float2(v0 + bi, v1 + bi);
}

// 2 edges per wave: lanes 0-31 -> edge 2k, lanes 32-63 -> edge 2k+1
// lane's half2 covers 2 batch elems; gather fp16 A[src], fp32 atomics into B[dst]
__global__ void edge_kernel(const float* __restrict__ w_edge,
                            const int* __restrict__ src,
                            const int* __restrict__ dst,
                            const __half2* __restrict__ A,
                            float* __restrict__ B,
                            int* __restrict__ flag) {
    int lane = threadIdx.x & 63;
    int half = lane >> 5;
    int sub  = lane & 31;
    int wid = (int)((blockIdx.x * blockDim.x + threadIdx.x) >> 6);
    int nw  = (int)((gridDim.x * blockDim.x) >> 6);
    const int npairs = NEDGES / 2;
    for (int ep = wid; ep < npairs; ep += nw) {
        int e = ep * 2 + half;
        int s = src[e];
        int d = dst[e];
        float w = w_edge[e];
        float2 f = __half22float2(A[(size_t)s * NB2 + sub]);
        float* bp = B + (size_t)d * NB + sub * 2;
        atomicAdd(bp,     w * f.x);
        atomicAdd(bp + 1, w * f.y);
        if (sub == 0) flag[d] = 1;
    }
}

// flagged nodes: t = tanh(B); A = t (fp16); B = t + bias (fp32); reset flag
__global__ void update_kernel(const float* __restrict__ bias,
                              __half2* __restrict__ A,
                              float2* __restrict__ B,
                              int* __restrict__ flag) {
    int tid = blockIdx.x * blockDim.x + threadIdx.x;
    int n = tid >> 5;
    int sub = tid & 31;
    if (n >= NNODES) return;
    if (flag[n] == 0) return;
    size_t idx = (size_t)n * NB2 + sub;
    float2 f = B[idx];
    float t0 = tanhf(f.x);
    float t1 = tanhf(f.y);
    A[idx] = __floats2half2_rn(t0, t1);
    float bn = bias[n];
    B[idx] = make_float2(t0 + bn, t1 + bn);
    if (sub == 0) flag[n] = 0;
}

// out[b][j] = A[N - NOUT + j][b] as fp32
__global__ void output_kernel(const __half* __restrict__ Ah,
                              float* __restrict__ out) {
    int tid = blockIdx.x * blockDim.x + threadIdx.x;
    if (tid >= NB * NOUT) return;
    int b = tid / NOUT;
    int j = tid % NOUT;
    out[tid] = __half2float(Ah[(size_t)(NNODES - NOUT + j) * NB + b]);
}

extern "C" void kernel_launch(void* const* d_in, const int* in_sizes, int n_in,
                              void* d_out, int out_size, void* d_ws, size_t ws_size,
                              hipStream_t stream) {
    const float* x      = (const float*)d_in[0];
    const float* w_in   = (const float*)d_in[1];
    const float* bias   = (const float*)d_in[2];
    const float* w_edge = (const float*)d_in[3];
    const int*   src    = (const int*)d_in[4];
    const int*   dst    = (const int*)d_in[5];
    float* out = (float*)d_out;

    __half2* A = (__half2*)d_ws;                        // 25.6 MB
    float*   B = (float*)(A + (size_t)NNODES * NB2);    // 51.2 MB
    int*  flag = (int*)(B + (size_t)NNODES * NB);       // 0.8 MB

    const int nthreads = NNODES * NB2;
    const int nblocks = (nthreads + 255) / 256;

    init_kernel<<<nblocks, 256, 0, stream>>>(bias, A, (float2*)B, flag);
    input_kernel<<<(NIN * NB2 + 255) / 256, 256, 0, stream>>>(x, w_in, bias, A, (float2*)B);

    const int eblocks = 8192;   // grid-stride over 500K wave-pair-tasks
    for (int s = 0; s < NSTEPS; ++s) {
        edge_kernel<<<eblocks, 256, 0, stream>>>(
            w_edge + (size_t)s * NEDGES, src + (size_t)s * NEDGES,
            dst + (size_t)s * NEDGES, A, B, flag);
        update_kernel<<<nblocks, 256, 0, stream>>>(bias, A, (float2*)B, flag);
    }

    output_kernel<<<(NB * NOUT + 255) / 256, 256, 0, stream>>>((const __half*)A, out);
}

// Round 4
// 1839.678 us; speedup vs baseline: 1.4862x; 1.4862x over previous
//
#include <hip/hip_runtime.h>
#include <hip/hip_fp16.h>

#define NB     64        // batch
#define NNODES 200000
#define NP1    (NNODES + 1)
#define NSTEPS 6
#define NEDGES 1000000
#define NIN    4096
#define NOUT   1024

// State A (fp16): A[n*64 + b]. Ping-pong A0/A1. No atomics on state.
// CSR built per call: H[s][n] = row offsets (via hist+scan), csr[s][k] = global edge id.

// input phase: nodes i < NIN get tanh(x*w_in + bias); rest stay 0 (memset)
__global__ void input_kernel(const float* __restrict__ x,
                             const float* __restrict__ w_in,
                             const float* __restrict__ bias,
                             __half* __restrict__ A0) {
    int tid = blockIdx.x * blockDim.x + threadIdx.x;
    int i = tid >> 6;
    int b = tid & 63;
    if (i >= NIN) return;
    float v = tanhf(x[(size_t)b * NIN + i] * w_in[i] + bias[i]);
    A0[(size_t)i * NB + b] = __float2half(v);
}

// histogram: H[s*NP1 + d + 1] += 1 for each edge (H pre-zeroed)
__global__ void hist_kernel(const int* __restrict__ dst, int* __restrict__ H) {
    int e = blockIdx.x * blockDim.x + threadIdx.x;
    if (e >= NSTEPS * NEDGES) return;
    int s = e / NEDGES;
    atomicAdd(&H[s * NP1 + dst[e] + 1], 1);
}

// in-place inclusive scan of each step's H row (one block per step)
// after scan: H[s][n] = start offset of node n's CSR row
__global__ void scan_kernel(int* __restrict__ H) {
    int* h = H + blockIdx.x * NP1;
    const int K = (NP1 + 1023) / 1024;   // 196 elems per thread
    int t = threadIdx.x;
    int lo = t * K;
    int hi = lo + K; if (hi > NP1) hi = NP1;
    int sum = 0;
    for (int i = lo; i < hi; i++) sum += h[i];
    // block exclusive scan of per-thread sums
    int lane = t & 63, wid = t >> 6;
    int v = sum;
    for (int off = 1; off < 64; off <<= 1) {
        int xx = __shfl_up(v, off);
        if (lane >= off) v += xx;
    }
    __shared__ int wsum[16];
    if (lane == 63) wsum[wid] = v;
    __syncthreads();
    int woff = 0;
    for (int ww = 0; ww < wid; ww++) woff += wsum[ww];
    int run = (v - sum) + woff;          // exclusive prefix for this thread
    for (int i = lo; i < hi; i++) { run += h[i]; h[i] = run; }
}

// scatter edge ids into CSR slots; H[s][d] used as cursor (start -> end)
__global__ void scatter_kernel(const int* __restrict__ dst,
                               int* __restrict__ H, int* __restrict__ csr) {
    int e = blockIdx.x * blockDim.x + threadIdx.x;
    if (e >= NSTEPS * NEDGES) return;
    int s = e / NEDGES;
    int slot = atomicAdd(&H[s * NP1 + dst[e]], 1);
    csr[(size_t)s * NEDGES + slot] = e;
}

// one wave per node: acc[b] = bias + A_old[n][b] + sum_e w_e * A_old[src_e][b]
// post-scatter: row start = (n==0) ? 0 : H[n-1], row end = H[n]
__global__ void pull_kernel(const float* __restrict__ bias,
                            const int* __restrict__ srcArr,
                            const float* __restrict__ wArr,
                            const int* __restrict__ H,
                            const int* __restrict__ csr,
                            const __half* __restrict__ Aold,
                            __half* __restrict__ Anew, int step) {
    int gw = (int)((blockIdx.x * blockDim.x + threadIdx.x) >> 6);
    int lane = threadIdx.x & 63;
    if (gw >= NNODES) return;
    int n = gw;
    const int* h = H + step * NP1;
    int end = h[n];
    int start = (n == 0) ? 0 : h[n - 1];
    size_t row = (size_t)n * NB + lane;
    __half aold = Aold[row];
    if (start == end) { Anew[row] = aold; return; }   // no fan-in: keep state
    float acc = __half2float(aold) + bias[n];
    const int* ecsr = csr + (size_t)step * NEDGES;
    for (int jb = start; jb < end; jb += 64) {
        int m = end - jb; if (m > 64) m = 64;
        int ev = 0, sv = 0; float wv = 0.f;
        if (lane < m) {                 // coalesced metadata tile
            ev = ecsr[jb + lane];
            sv = srcArr[ev];
            wv = wArr[ev];
        }
        for (int k = 0; k < m; k++) {   // broadcast + independent gathers
            int sk = __shfl(sv, k);
            float wk = __shfl(wv, k);
            acc += wk * __half2float(Aold[(size_t)sk * NB + lane]);
        }
    }
    Anew[row] = __float2half(tanhf(acc));
}

// out[b][j] = A[N - NOUT + j][b] as fp32
__global__ void output_kernel(const __half* __restrict__ A,
                              float* __restrict__ out) {
    int tid = blockIdx.x * blockDim.x + threadIdx.x;
    if (tid >= NB * NOUT) return;
    int b = tid / NOUT;
    int j = tid % NOUT;
    out[tid] = __half2float(A[(size_t)(NNODES - NOUT + j) * NB + b]);
}

extern "C" void kernel_launch(void* const* d_in, const int* in_sizes, int n_in,
                              void* d_out, int out_size, void* d_ws, size_t ws_size,
                              hipStream_t stream) {
    const float* x      = (const float*)d_in[0];
    const float* w_in   = (const float*)d_in[1];
    const float* bias   = (const float*)d_in[2];
    const float* w_edge = (const float*)d_in[3];   // [S*E] flat
    const int*   src    = (const int*)d_in[4];     // [S*E] flat
    const int*   dst    = (const int*)d_in[5];     // [S*E] flat
    float* out = (float*)d_out;

    char* ws = (char*)d_ws;
    __half* A0 = (__half*)ws;                                  ws += (size_t)NNODES * NB * 2;  // 25.6 MB
    __half* A1 = (__half*)ws;                                  ws += (size_t)NNODES * NB * 2;  // 25.6 MB
    int*    H  = (int*)ws;                                     ws += (size_t)NSTEPS * NP1 * 4; // 4.8 MB
    int*    csr = (int*)ws;                                    // 24 MB

    // zero state + histogram (ws is poisoned 0xAA each call)
    hipMemsetAsync(A0, 0, (size_t)NNODES * NB * 2, stream);
    hipMemsetAsync(H, 0, (size_t)NSTEPS * NP1 * 4, stream);

    input_kernel<<<(NIN * NB + 255) / 256, 256, 0, stream>>>(x, w_in, bias, A0);

    const int etot = NSTEPS * NEDGES;
    hist_kernel<<<(etot + 255) / 256, 256, 0, stream>>>(dst, H);
    scan_kernel<<<NSTEPS, 1024, 0, stream>>>(H);
    scatter_kernel<<<(etot + 255) / 256, 256, 0, stream>>>(dst, H, csr);

    const int pblocks = (NNODES + 3) / 4;   // 4 waves per block, 1 wave per node
    __half* cur = A0; __half* nxt = A1;
    for (int s = 0; s < NSTEPS; ++s) {
        pull_kernel<<<pblocks, 256, 0, stream>>>(bias, src, w_edge, H, csr, cur, nxt, s);
        __half* t = cur; cur = nxt; nxt = t;
    }

    output_kernel<<<(NB * NOUT + 255) / 256, 256, 0, stream>>>(cur, out);
}